// Round 10
// baseline (307.251 us; speedup 1.0000x reference)
//
#include <hip/hip_runtime.h>
#include <math.h>
#include <stdint.h>

#define B_ROWS 2048
#define D_DIM  512
#define V_COLS 32000
#define BM 128
#define BN 256
#define BK 64
#define KSTEPS (D_DIM / BK)             // 8
#define NRT    (B_ROWS / BM)            // 16 row tiles
#define NCT    (V_COLS / BN)            // 125 col tiles
#define S_SC   30.0f
#define COS_M  0.8775825618903728f      // cos(0.5)
#define SIN_M  0.479425538604203f       // sin(0.5)

typedef float f32x4 __attribute__((ext_vector_type(4)));
typedef long  i64x2 __attribute__((ext_vector_type(2)));

__device__ __forceinline__ void load16_to_lds(const void* g, void* l) {
  __builtin_amdgcn_global_load_lds(
      (__attribute__((address_space(1))) void*)(g),
      (__attribute__((address_space(3))) void*)(l),
      16, 0, 0);
}

// ---------- kernel 1: fused row L2-normalize (x,W) fp32 -> fp8 e4m3, + zero out ----------
__global__ void fused_norm_kernel(const float* __restrict__ x,
                                  const float* __restrict__ W,
                                  uint8_t* __restrict__ nx,
                                  uint8_t* __restrict__ nw,
                                  float* __restrict__ out) {
  if (blockIdx.x == 0 && threadIdx.x == 0) out[0] = 0.f;
  const int lane = threadIdx.x & 63;
  const int wave = threadIdx.x >> 6;
  const int gr   = blockIdx.x * 4 + wave;
  const float* src;
  uint8_t* dst;
  if (gr < B_ROWS) {
    src = x + (size_t)gr * D_DIM;
    dst = nx + (size_t)gr * D_DIM;
  } else {
    src = W + (size_t)(gr - B_ROWS) * D_DIM;
    dst = nw + (size_t)(gr - B_ROWS) * D_DIM;
  }
  const float4* r4 = (const float4*)src;
  float4 v0 = r4[2 * lane];
  float4 v1 = r4[2 * lane + 1];
  float ss = v0.x*v0.x + v0.y*v0.y + v0.z*v0.z + v0.w*v0.w
           + v1.x*v1.x + v1.y*v1.y + v1.z*v1.z + v1.w*v1.w;
  #pragma unroll
  for (int off = 32; off >= 1; off >>= 1) ss += __shfl_xor(ss, off, 64);
  float inv = 1.0f / fmaxf(sqrtf(ss), 1e-12f);
  int p0 = __builtin_amdgcn_cvt_pk_fp8_f32(v0.x * inv, v0.y * inv, 0, false);
  p0     = __builtin_amdgcn_cvt_pk_fp8_f32(v0.z * inv, v0.w * inv, p0, true);
  int p1 = __builtin_amdgcn_cvt_pk_fp8_f32(v1.x * inv, v1.y * inv, 0, false);
  p1     = __builtin_amdgcn_cvt_pk_fp8_f32(v1.z * inv, v1.w * inv, p1, true);
  ((int2*)dst)[lane] = make_int2(p0, p1);
}

// ---------- kernel 2: fp8 GEMM (nx @ nW^T), 128x256 tile, PROVEN 2-barrier schedule ----------
// R20: R9's decomposition leaves the GEMM (70 us, MfmaUtil 38%, 959 TF = ~96% of the
// m145-class ceiling for the 128^2 2-barrier loop) as the only lever. Unlike the
// failed R1/R2 rewrites (which changed schedule AND collapsed to 1 block/CU), this
// keeps the proven 2-barrier dbuf schedule byte-for-byte and ONLY widens the tile:
//   BM=128 x BN=256, 512 threads, 8 waves (2M x 4N), wave tile 64x64 (same acc[4][4],
//   same per-wave MFMA count, same involution math -- wm*64, mi*16 are 0 mod 8).
//   Staging: 3 loads/thread/K-step (A:1, B:2) vs 4 before -> 25% less stall work
//   per barrier for the same compute. LDS 48 KB -> 3 blocks/CU x 8 waves = 24
//   waves/CU (MORE inter-block overlap than R9's ~16).
//   Grid 16x125 = 2000 blocks; 2000%8==0 -> exact bijective XCD swizzle; 16
//   consecutive blocks per XCD share one 128 KB B-panel in its L2.
__global__ __launch_bounds__(512, 6)
void arc_gemm_kernel(const uint8_t* __restrict__ nx,
                     const uint8_t* __restrict__ nw,
                     const int* __restrict__ labels,
                     float* __restrict__ part,
                     float* __restrict__ lbl_logit) {
  __shared__ uint8_t sA[2][BM * BK];   // 2 x 8 KB
  __shared__ uint8_t sB[2][BN * BK];   // 2 x 16 KB  (48 KB total)

  const int id = blockIdx.x;
  const int wg = (id & 7) * 250 + (id >> 3);   // bijective: XCD k owns wg [250k, 250k+250)
  const int rt = wg & 15;                      // row tile 0..15 (fastest -> B-panel reuse)
  const int ctile = wg >> 4;                   // col tile 0..124
  const int m0 = rt * BM;
  const int n0 = ctile * BN;

  const int tid  = threadIdx.x;
  const int wave = tid >> 6;          // 0..7
  const int lane = tid & 63;
  const int wm   = wave >> 2;         // 0..1
  const int wn   = wave & 3;          // 0..3
  const int quad = lane >> 4;
  const int l16  = lane & 15;

  // staging: thread covers row srow (A; B rows srow and 128+srow), 16B chunk jg.
  // involution: LDS[row][slot] holds global chunk slot ^ ((row>>1)&3).
  const int srow = tid >> 2;          // 0..127
  const int jg   = (tid & 3) ^ ((srow >> 1) & 3);
  const uint8_t* gA = nx + (size_t)(m0 + srow) * D_DIM + jg * 16;
  const uint8_t* gB = nw + (size_t)(n0 + srow) * D_DIM + jg * 16;
  const int ldsW = wave * 1024;       // wave-uniform base; HW adds lane*16

  // frag reads: row stride 64 B, 16B slot XOR swizzle (measured-zero-conflict math)
  const int cSlot = (quad ^ ((l16 >> 1) & 3)) << 4;
  const int aBase = (wm * 64 + l16) * BK + cSlot;   // + mi*16*BK
  const int bBase = (wn * 64 + l16) * BK + cSlot;   // + ni*16*BK

  f32x4 acc[4][4];
  #pragma unroll
  for (int i = 0; i < 4; ++i)
    #pragma unroll
    for (int j = 0; j < 4; ++j) acc[i][j] = (f32x4){0.f, 0.f, 0.f, 0.f};

#define STAGE(buf, t) do {                                        \
    const int _o = (t) * BK;                                      \
    load16_to_lds(gA + _o,               &sA[(buf)][ldsW]);       \
    load16_to_lds(gB + _o,               &sB[(buf)][ldsW]);       \
    load16_to_lds(gB + 128 * D_DIM + _o, &sB[(buf)][8192 + ldsW]);\
  } while (0)

  // prologue: tile 0 -> buf 0
  STAGE(0, 0);

  #pragma unroll
  for (int ks = 0; ks < KSTEPS; ++ks) {
    __syncthreads();                          // prev compute done before overwrite
    if (ks + 1 < KSTEPS) STAGE((ks + 1) & 1, ks + 1);
    __syncthreads();                          // tile ks resident

    const uint8_t* bA = sA[ks & 1];
    const uint8_t* bB = sB[ks & 1];
    i64x2 a2[4];
    #pragma unroll
    for (int mi = 0; mi < 4; ++mi)
      a2[mi] = *(const i64x2*)(bA + aBase + mi * 16 * BK);
    #pragma unroll
    for (int ni = 0; ni < 4; ++ni) {
      const i64x2 b2 = *(const i64x2*)(bB + bBase + ni * 16 * BK);
      #pragma unroll
      for (int mi = 0; mi < 4; ++mi) {
        acc[mi][ni] = __builtin_amdgcn_mfma_f32_16x16x32_fp8_fp8(a2[mi][0], b2[0], acc[mi][ni], 0, 0, 0);
        acc[mi][ni] = __builtin_amdgcn_mfma_f32_16x16x32_fp8_fp8(a2[mi][1], b2[1], acc[mi][ni], 0, 0, 0);
      }
    }
  }
#undef STAGE

  // Epilogue (R4-proven math). C/D layout: col = lane&15, row = quad*4 + reg.
  const int lblv = labels[m0 + wm * 64 + lane];
  const int pcol = (ctile << 2) | wn;         // 0..499, block/wave-uniform
  #pragma unroll
  for (int mi = 0; mi < 4; ++mi) {
    #pragma unroll
    for (int r = 0; r < 4; ++r) {
      const int rw   = mi * 16 + quad * 4 + r;
      const int grow = m0 + wm * 64 + rw;
      const int lbl  = __shfl(lblv, rw, 64);
      float rsum = 0.f;
      #pragma unroll
      for (int ni = 0; ni < 4; ++ni) {
        float c = acc[mi][ni][r];
        const int gcol = n0 + wn * 64 + ni * 16 + l16;
        if (gcol == lbl) {
          float sy  = sqrtf(fminf(1.f, fmaxf(0.f, 1.f - c * c)));
          float phi = c * COS_M - sy * SIN_M;
          lbl_logit[grow] = S_SC * phi;       // exactly one lane grid-wide
          c = phi;
        }
        rsum += __expf(S_SC * c - 30.0f);     // fixed shift: logits in [-30,30]
      }
      #pragma unroll
      for (int off = 1; off < 16; off <<= 1)
        rsum += __shfl_xor(rsum, off, 64);
      if (l16 == 0) part[((size_t)grow << 9) + pcol] = rsum;   // plain store, no RMW
    }
  }
}

// ---------- kernel 3: per-row partial reduce + loss + global mean ----------
// One wave per row (512 blocks x 4 waves): lanes read the row's 125 float4 coalesced,
// shfl_xor reduce. R9-proven (~2-3 us).
__global__ void arc_finish_kernel(const float* __restrict__ part,
                                  const float* __restrict__ lbl_logit,
                                  float* __restrict__ out) {
  const int tid  = threadIdx.x;
  const int lane = tid & 63;
  const int wave = tid >> 6;
  const int row  = blockIdx.x * 4 + wave;     // 512 blocks x 4 waves = 2048 rows
  const float4* p4 = (const float4*)(part + ((size_t)row << 9));
  float4 q0 = p4[lane];                       // entries 0..63
  float s = (q0.x + q0.y) + (q0.z + q0.w);
  if (lane < 61) {                            // entries 64..124 (125 total = 500 floats)
    float4 q1 = p4[64 + lane];
    s += (q1.x + q1.y) + (q1.z + q1.w);
  }
  #pragma unroll
  for (int off = 32; off >= 1; off >>= 1) s += __shfl_xor(s, off, 64);
  __shared__ float wsum[4];
  if (lane == 0)
    wsum[wave] = (30.0f + logf(s) - lbl_logit[row]) * (1.0f / (float)B_ROWS);
  __syncthreads();
  if (tid == 0) atomicAdd(out, wsum[0] + wsum[1] + wsum[2] + wsum[3]);
}

// ---------- launch ----------
extern "C" void kernel_launch(void* const* d_in, const int* in_sizes, int n_in,
                              void* d_out, int out_size, void* d_ws, size_t ws_size,
                              hipStream_t stream) {
  const float* x      = (const float*)d_in[0];
  const float* W      = (const float*)d_in[1];
  const int*   labels = (const int*)d_in[2];
  float* out = (float*)d_out;

  char* ws = (char*)d_ws;
  uint8_t* nx = (uint8_t*)ws;                                       // 1 MB
  uint8_t* nw = (uint8_t*)(ws + (size_t)B_ROWS * D_DIM);            // 16.4 MB
  char* p = ws + (size_t)B_ROWS * D_DIM + (size_t)V_COLS * D_DIM;
  float* lbl_logit = (float*)p;  p += (size_t)B_ROWS * 4;           // 8 KB
  float* part      = (float*)p;                                     // 2048 x 512 f32 = 4 MB

  hipLaunchKernelGGL(fused_norm_kernel, dim3((B_ROWS + V_COLS) / 4), dim3(256), 0, stream,
                     x, W, nx, nw, out);
  hipLaunchKernelGGL(arc_gemm_kernel, dim3(NRT * NCT), dim3(512), 0, stream,
                     nx, nw, labels, part, lbl_logit);
  hipLaunchKernelGGL(arc_finish_kernel, dim3(B_ROWS / 4), dim3(256), 0, stream,
                     part, lbl_logit, out);
}

// Round 11
// 170.238 us; speedup vs baseline: 1.8048x; 1.8048x over previous
//
#include <hip/hip_runtime.h>
#include <math.h>
#include <stdint.h>

#define B_ROWS 2048
#define D_DIM  512
#define V_COLS 32000
#define BM 128
#define BN 256
#define BK 64
#define KSTEPS (D_DIM / BK)             // 8
#define NRT    (B_ROWS / BM)            // 16 row tiles
#define NCT    (V_COLS / BN)            // 125 col tiles
#define S_SC   30.0f
#define COS_M  0.8775825618903728f      // cos(0.5)
#define SIN_M  0.479425538604203f       // sin(0.5)

typedef float f32x4 __attribute__((ext_vector_type(4)));
typedef long  i64x2 __attribute__((ext_vector_type(2)));

__device__ __forceinline__ void load16_to_lds(const void* g, void* l) {
  __builtin_amdgcn_global_load_lds(
      (__attribute__((address_space(1))) void*)(g),
      (__attribute__((address_space(3))) void*)(l),
      16, 0, 0);
}

// ---------- kernel 1: fused row L2-normalize (x,W) fp32 -> fp8 e4m3, + zero out ----------
__global__ void fused_norm_kernel(const float* __restrict__ x,
                                  const float* __restrict__ W,
                                  uint8_t* __restrict__ nx,
                                  uint8_t* __restrict__ nw,
                                  float* __restrict__ out) {
  if (blockIdx.x == 0 && threadIdx.x == 0) out[0] = 0.f;
  const int lane = threadIdx.x & 63;
  const int wave = threadIdx.x >> 6;
  const int gr   = blockIdx.x * 4 + wave;
  const float* src;
  uint8_t* dst;
  if (gr < B_ROWS) {
    src = x + (size_t)gr * D_DIM;
    dst = nx + (size_t)gr * D_DIM;
  } else {
    src = W + (size_t)(gr - B_ROWS) * D_DIM;
    dst = nw + (size_t)(gr - B_ROWS) * D_DIM;
  }
  const float4* r4 = (const float4*)src;
  float4 v0 = r4[2 * lane];
  float4 v1 = r4[2 * lane + 1];
  float ss = v0.x*v0.x + v0.y*v0.y + v0.z*v0.z + v0.w*v0.w
           + v1.x*v1.x + v1.y*v1.y + v1.z*v1.z + v1.w*v1.w;
  #pragma unroll
  for (int off = 32; off >= 1; off >>= 1) ss += __shfl_xor(ss, off, 64);
  float inv = 1.0f / fmaxf(sqrtf(ss), 1e-12f);
  int p0 = __builtin_amdgcn_cvt_pk_fp8_f32(v0.x * inv, v0.y * inv, 0, false);
  p0     = __builtin_amdgcn_cvt_pk_fp8_f32(v0.z * inv, v0.w * inv, p0, true);
  int p1 = __builtin_amdgcn_cvt_pk_fp8_f32(v1.x * inv, v1.y * inv, 0, false);
  p1     = __builtin_amdgcn_cvt_pk_fp8_f32(v1.z * inv, v1.w * inv, p1, true);
  ((int2*)dst)[lane] = make_int2(p0, p1);
}

// ---------- kernel 2: fp8 GEMM (nx @ nW^T), 128x256 tile, PROVEN 2-barrier schedule ----------
// R21 = R20 with ONE fix. R20's __launch_bounds__(512, 6) capped the allocator at
// ~85 regs (VGPR_Count 40!) and spilled the 64-reg accumulator to scratch: FETCH
// 223 MB / WRITE 484 MB, MfmaUtil 12% -- the R5 spill signature, self-inflicted.
// The tile theory was never tested. Fix: __launch_bounds__(512, 2) (cap 256; natural
// use ~100-110). Theory unchanged: same proven 2-barrier dbuf schedule as R9's 70-us
// kernel, only wider: BM=128 x BN=256, 512 threads, 8 waves (2M x 4N), wave tile
// 64x64 (same acc[4][4], same per-wave MFMA count, same involution). Staging drops
// to 3 loads/thread/K-step (vs 4) for the same compute -> 25% less stall work per
// barrier. LDS 48 KB -> ~3 blocks/CU; grid 2000 = 8 x 250 -> exact XCD swizzle,
// 16 consecutive blocks/XCD share a 128 KB B-panel in L2.
__global__ __launch_bounds__(512, 2)
void arc_gemm_kernel(const uint8_t* __restrict__ nx,
                     const uint8_t* __restrict__ nw,
                     const int* __restrict__ labels,
                     float* __restrict__ part,
                     float* __restrict__ lbl_logit) {
  __shared__ uint8_t sA[2][BM * BK];   // 2 x 8 KB
  __shared__ uint8_t sB[2][BN * BK];   // 2 x 16 KB  (48 KB total)

  const int id = blockIdx.x;
  const int wg = (id & 7) * 250 + (id >> 3);   // bijective: XCD k owns wg [250k, 250k+250)
  const int rt = wg & 15;                      // row tile 0..15 (fastest -> B-panel reuse)
  const int ctile = wg >> 4;                   // col tile 0..124
  const int m0 = rt * BM;
  const int n0 = ctile * BN;

  const int tid  = threadIdx.x;
  const int wave = tid >> 6;          // 0..7
  const int lane = tid & 63;
  const int wm   = wave >> 2;         // 0..1
  const int wn   = wave & 3;          // 0..3
  const int quad = lane >> 4;
  const int l16  = lane & 15;

  // staging: thread covers row srow (A; B rows srow and 128+srow), 16B chunk jg.
  // involution: LDS[row][slot] holds global chunk slot ^ ((row>>1)&3).
  const int srow = tid >> 2;          // 0..127
  const int jg   = (tid & 3) ^ ((srow >> 1) & 3);
  const uint8_t* gA = nx + (size_t)(m0 + srow) * D_DIM + jg * 16;
  const uint8_t* gB = nw + (size_t)(n0 + srow) * D_DIM + jg * 16;
  const int ldsW = wave * 1024;       // wave-uniform base; HW adds lane*16

  // frag reads: row stride 64 B, 16B slot XOR swizzle (measured-zero-conflict math)
  const int cSlot = (quad ^ ((l16 >> 1) & 3)) << 4;
  const int aBase = (wm * 64 + l16) * BK + cSlot;   // + mi*16*BK
  const int bBase = (wn * 64 + l16) * BK + cSlot;   // + ni*16*BK

  f32x4 acc[4][4];
  #pragma unroll
  for (int i = 0; i < 4; ++i)
    #pragma unroll
    for (int j = 0; j < 4; ++j) acc[i][j] = (f32x4){0.f, 0.f, 0.f, 0.f};

#define STAGE(buf, t) do {                                        \
    const int _o = (t) * BK;                                      \
    load16_to_lds(gA + _o,               &sA[(buf)][ldsW]);       \
    load16_to_lds(gB + _o,               &sB[(buf)][ldsW]);       \
    load16_to_lds(gB + 128 * D_DIM + _o, &sB[(buf)][8192 + ldsW]);\
  } while (0)

  // prologue: tile 0 -> buf 0
  STAGE(0, 0);

  #pragma unroll
  for (int ks = 0; ks < KSTEPS; ++ks) {
    __syncthreads();                          // prev compute done before overwrite
    if (ks + 1 < KSTEPS) STAGE((ks + 1) & 1, ks + 1);
    __syncthreads();                          // tile ks resident

    const uint8_t* bA = sA[ks & 1];
    const uint8_t* bB = sB[ks & 1];
    i64x2 a2[4];
    #pragma unroll
    for (int mi = 0; mi < 4; ++mi)
      a2[mi] = *(const i64x2*)(bA + aBase + mi * 16 * BK);
    #pragma unroll
    for (int ni = 0; ni < 4; ++ni) {
      const i64x2 b2 = *(const i64x2*)(bB + bBase + ni * 16 * BK);
      #pragma unroll
      for (int mi = 0; mi < 4; ++mi) {
        acc[mi][ni] = __builtin_amdgcn_mfma_f32_16x16x32_fp8_fp8(a2[mi][0], b2[0], acc[mi][ni], 0, 0, 0);
        acc[mi][ni] = __builtin_amdgcn_mfma_f32_16x16x32_fp8_fp8(a2[mi][1], b2[1], acc[mi][ni], 0, 0, 0);
      }
    }
  }
#undef STAGE

  // Epilogue (R4-proven math). C/D layout: col = lane&15, row = quad*4 + reg.
  const int lblv = labels[m0 + wm * 64 + lane];
  const int pcol = (ctile << 2) | wn;         // 0..499, block/wave-uniform
  #pragma unroll
  for (int mi = 0; mi < 4; ++mi) {
    #pragma unroll
    for (int r = 0; r < 4; ++r) {
      const int rw   = mi * 16 + quad * 4 + r;
      const int grow = m0 + wm * 64 + rw;
      const int lbl  = __shfl(lblv, rw, 64);
      float rsum = 0.f;
      #pragma unroll
      for (int ni = 0; ni < 4; ++ni) {
        float c = acc[mi][ni][r];
        const int gcol = n0 + wn * 64 + ni * 16 + l16;
        if (gcol == lbl) {
          float sy  = sqrtf(fminf(1.f, fmaxf(0.f, 1.f - c * c)));
          float phi = c * COS_M - sy * SIN_M;
          lbl_logit[grow] = S_SC * phi;       // exactly one lane grid-wide
          c = phi;
        }
        rsum += __expf(S_SC * c - 30.0f);     // fixed shift: logits in [-30,30]
      }
      #pragma unroll
      for (int off = 1; off < 16; off <<= 1)
        rsum += __shfl_xor(rsum, off, 64);
      if (l16 == 0) part[((size_t)grow << 9) + pcol] = rsum;   // plain store, no RMW
    }
  }
}

// ---------- kernel 3: per-row partial reduce + loss + global mean ----------
// One wave per row (512 blocks x 4 waves): lanes read the row's 125 float4 coalesced,
// shfl_xor reduce. R9-proven (~2-3 us).
__global__ void arc_finish_kernel(const float* __restrict__ part,
                                  const float* __restrict__ lbl_logit,
                                  float* __restrict__ out) {
  const int tid  = threadIdx.x;
  const int lane = tid & 63;
  const int wave = tid >> 6;
  const int row  = blockIdx.x * 4 + wave;     // 512 blocks x 4 waves = 2048 rows
  const float4* p4 = (const float4*)(part + ((size_t)row << 9));
  float4 q0 = p4[lane];                       // entries 0..63
  float s = (q0.x + q0.y) + (q0.z + q0.w);
  if (lane < 61) {                            // entries 64..124 (125 total = 500 floats)
    float4 q1 = p4[64 + lane];
    s += (q1.x + q1.y) + (q1.z + q1.w);
  }
  #pragma unroll
  for (int off = 32; off >= 1; off >>= 1) s += __shfl_xor(s, off, 64);
  __shared__ float wsum[4];
  if (lane == 0)
    wsum[wave] = (30.0f + logf(s) - lbl_logit[row]) * (1.0f / (float)B_ROWS);
  __syncthreads();
  if (tid == 0) atomicAdd(out, wsum[0] + wsum[1] + wsum[2] + wsum[3]);
}

// ---------- launch ----------
extern "C" void kernel_launch(void* const* d_in, const int* in_sizes, int n_in,
                              void* d_out, int out_size, void* d_ws, size_t ws_size,
                              hipStream_t stream) {
  const float* x      = (const float*)d_in[0];
  const float* W      = (const float*)d_in[1];
  const int*   labels = (const int*)d_in[2];
  float* out = (float*)d_out;

  char* ws = (char*)d_ws;
  uint8_t* nx = (uint8_t*)ws;                                       // 1 MB
  uint8_t* nw = (uint8_t*)(ws + (size_t)B_ROWS * D_DIM);            // 16.4 MB
  char* p = ws + (size_t)B_ROWS * D_DIM + (size_t)V_COLS * D_DIM;
  float* lbl_logit = (float*)p;  p += (size_t)B_ROWS * 4;           // 8 KB
  float* part      = (float*)p;                                     // 2048 x 512 f32 = 4 MB

  hipLaunchKernelGGL(fused_norm_kernel, dim3((B_ROWS + V_COLS) / 4), dim3(256), 0, stream,
                     x, W, nx, nw, out);
  hipLaunchKernelGGL(arc_gemm_kernel, dim3(NRT * NCT), dim3(512), 0, stream,
                     nx, nw, labels, part, lbl_logit);
  hipLaunchKernelGGL(arc_finish_kernel, dim3(B_ROWS / 4), dim3(256), 0, stream,
                     part, lbl_logit, out);
}

// Round 12
// 163.951 us; speedup vs baseline: 1.8740x; 1.0383x over previous
//
#include <hip/hip_runtime.h>
#include <math.h>
#include <stdint.h>

#define B_ROWS 2048
#define D_DIM  512
#define V_COLS 32000
#define BM 128
#define BN 128
#define BK 64
#define KSTEPS (D_DIM / BK)             // 8
#define NCT    (V_COLS / BN)            // 250 col tiles
#define S_SC   30.0f
#define COS_M  0.8775825618903728f      // cos(0.5)
#define SIN_M  0.479425538604203f       // sin(0.5)

typedef float f32x4 __attribute__((ext_vector_type(4)));
typedef long  i64x2 __attribute__((ext_vector_type(2)));

__device__ __forceinline__ void load16_to_lds(const void* g, void* l) {
  __builtin_amdgcn_global_load_lds(
      (__attribute__((address_space(1))) void*)(g),
      (__attribute__((address_space(3))) void*)(l),
      16, 0, 0);
}

// ---------- kernel 1: fused row L2-normalize (x,W) fp32 -> fp8 e4m3, + zero out ----------
__global__ void fused_norm_kernel(const float* __restrict__ x,
                                  const float* __restrict__ W,
                                  uint8_t* __restrict__ nx,
                                  uint8_t* __restrict__ nw,
                                  float* __restrict__ out) {
  if (blockIdx.x == 0 && threadIdx.x == 0) out[0] = 0.f;
  const int lane = threadIdx.x & 63;
  const int wave = threadIdx.x >> 6;
  const int gr   = blockIdx.x * 4 + wave;
  const float* src;
  uint8_t* dst;
  if (gr < B_ROWS) {
    src = x + (size_t)gr * D_DIM;
    dst = nx + (size_t)gr * D_DIM;
  } else {
    src = W + (size_t)(gr - B_ROWS) * D_DIM;
    dst = nw + (size_t)(gr - B_ROWS) * D_DIM;
  }
  const float4* r4 = (const float4*)src;
  float4 v0 = r4[2 * lane];
  float4 v1 = r4[2 * lane + 1];
  float ss = v0.x*v0.x + v0.y*v0.y + v0.z*v0.z + v0.w*v0.w
           + v1.x*v1.x + v1.y*v1.y + v1.z*v1.z + v1.w*v1.w;
  #pragma unroll
  for (int off = 32; off >= 1; off >>= 1) ss += __shfl_xor(ss, off, 64);
  float inv = 1.0f / fmaxf(sqrtf(ss), 1e-12f);
  int p0 = __builtin_amdgcn_cvt_pk_fp8_f32(v0.x * inv, v0.y * inv, 0, false);
  p0     = __builtin_amdgcn_cvt_pk_fp8_f32(v0.z * inv, v0.w * inv, p0, true);
  int p1 = __builtin_amdgcn_cvt_pk_fp8_f32(v1.x * inv, v1.y * inv, 0, false);
  p1     = __builtin_amdgcn_cvt_pk_fp8_f32(v1.z * inv, v1.w * inv, p1, true);
  ((int2*)dst)[lane] = make_int2(p0, p1);
}

// ---------- kernel 2: fp8 GEMM (nx @ nW^T) -- TERMINAL: R9 restored verbatim ----------
// R22 = R9 (165.0 us total, gemm 70 us @ 959 TF fp8, MfmaUtil 38%). R11's clean-
// counter test falsified the last open theory (128x256 tile: 80 us -- halved block
// count starves the inter-block overlap that feeds the MFMA pipe). Session ledger of
// falsified alternatives against this structure: R1/R2 fine phase schedules, R3
// cooperative fusion (proved ~85 us fixed harness overhead, dispatch-independent),
// R4 counted-vmcnt triple-buffer, R5/R6 MX-scaled 32x32x64 (latency-bound at equal
// occupancy), R10/R11 wider tile. The one absorbed win: R17's atomic->plain-store
// (L2 RMW serialization removal, 87->73 us) + R18's wave-per-row finish (~17->2 us).
// Decomposition at rest: ~82 fixed + ~13 norm (BW floor) + ~70 gemm (structure
// ceiling) + ~2 finish ~= 165-170 us.
__global__ __launch_bounds__(256, 4)
void arc_gemm_kernel(const uint8_t* __restrict__ nx,
                     const uint8_t* __restrict__ nw,
                     const int* __restrict__ labels,
                     float* __restrict__ part,
                     float* __restrict__ lbl_logit) {
  __shared__ uint8_t sA[2][BM * BK];   // 2 x 8 KB
  __shared__ uint8_t sB[2][BN * BK];   // 2 x 8 KB

  const int id = blockIdx.x;
  const int ct = ((id >> 7) << 3) | (id & 7);
  if (ct >= NCT) return;
  const int rt = (id >> 3) & 15;
  const int m0 = rt * BM;
  const int n0 = ct * BN;

  const int tid  = threadIdx.x;
  const int wave = tid >> 6;
  const int lane = tid & 63;
  const int wm   = wave >> 1;
  const int wn   = wave & 1;
  const int quad = lane >> 4;
  const int l16  = lane & 15;

  // staging: inst i covers rows i*64 + (tid>>2); slot tid&3 <- global 16B chunk jg.
  const int srow = tid >> 2;
  const int jg   = (tid & 3) ^ ((srow >> 1) & 3);
  const uint8_t* gA = nx + (size_t)(m0 + srow) * D_DIM + jg * 16;
  const uint8_t* gB = nw + (size_t)(n0 + srow) * D_DIM + jg * 16;
  const int ldsOff0 = wave * 1024;          // wave-uniform LDS byte bases
  const int ldsOff1 = 4096 + wave * 1024;

  // frag reads: row stride 64 B, 16B slot XOR swizzle (measured-zero-conflict math)
  const int cSlot = (quad ^ ((l16 >> 1) & 3)) << 4;
  const int aBase = (wm * 64 + l16) * BK + cSlot;   // + mi*16*BK
  const int bBase = (wn * 64 + l16) * BK + cSlot;   // + ni*16*BK

  f32x4 acc[4][4];
  #pragma unroll
  for (int i = 0; i < 4; ++i)
    #pragma unroll
    for (int j = 0; j < 4; ++j) acc[i][j] = (f32x4){0.f, 0.f, 0.f, 0.f};

  // prologue: tile 0 -> buf 0
  load16_to_lds(gA,              &sA[0][ldsOff0]);
  load16_to_lds(gA + 64 * D_DIM, &sA[0][ldsOff1]);
  load16_to_lds(gB,              &sB[0][ldsOff0]);
  load16_to_lds(gB + 64 * D_DIM, &sB[0][ldsOff1]);

  #pragma unroll
  for (int ks = 0; ks < KSTEPS; ++ks) {
    __syncthreads();                          // prev compute done before overwrite
    if (ks + 1 < KSTEPS) {
      const int off = (ks + 1) * BK;
      const int nb  = (ks + 1) & 1;
      load16_to_lds(gA + off,              &sA[nb][ldsOff0]);
      load16_to_lds(gA + 64 * D_DIM + off, &sA[nb][ldsOff1]);
      load16_to_lds(gB + off,              &sB[nb][ldsOff0]);
      load16_to_lds(gB + 64 * D_DIM + off, &sB[nb][ldsOff1]);
    }
    __syncthreads();                          // tile ks resident

    const uint8_t* bA = sA[ks & 1];
    const uint8_t* bB = sB[ks & 1];
    i64x2 a2[4];
    #pragma unroll
    for (int mi = 0; mi < 4; ++mi)
      a2[mi] = *(const i64x2*)(bA + aBase + mi * 16 * BK);
    #pragma unroll
    for (int ni = 0; ni < 4; ++ni) {
      const i64x2 b2 = *(const i64x2*)(bB + bBase + ni * 16 * BK);
      #pragma unroll
      for (int mi = 0; mi < 4; ++mi) {
        acc[mi][ni] = __builtin_amdgcn_mfma_f32_16x16x32_fp8_fp8(a2[mi][0], b2[0], acc[mi][ni], 0, 0, 0);
        acc[mi][ni] = __builtin_amdgcn_mfma_f32_16x16x32_fp8_fp8(a2[mi][1], b2[1], acc[mi][ni], 0, 0, 0);
      }
    }
  }

  // Epilogue (R4-proven math). C/D layout: col = lane&15, row = quad*4 + reg.
  const int lblv = labels[m0 + wm * 64 + lane];
  const int pcol = (ct << 1) | wn;            // 0..499, block/wave-uniform
  #pragma unroll
  for (int mi = 0; mi < 4; ++mi) {
    #pragma unroll
    for (int r = 0; r < 4; ++r) {
      const int rw   = mi * 16 + quad * 4 + r;
      const int grow = m0 + wm * 64 + rw;
      const int lbl  = __shfl(lblv, rw, 64);
      float rsum = 0.f;
      #pragma unroll
      for (int ni = 0; ni < 4; ++ni) {
        float c = acc[mi][ni][r];
        const int gcol = n0 + wn * 64 + ni * 16 + l16;
        if (gcol == lbl) {
          float sy  = sqrtf(fminf(1.f, fmaxf(0.f, 1.f - c * c)));
          float phi = c * COS_M - sy * SIN_M;
          lbl_logit[grow] = S_SC * phi;       // exactly one lane grid-wide
          c = phi;
        }
        rsum += __expf(S_SC * c - 30.0f);     // fixed shift: logits in [-30,30]
      }
      #pragma unroll
      for (int off = 1; off < 16; off <<= 1)
        rsum += __shfl_xor(rsum, off, 64);
      if (l16 == 0) part[((size_t)grow << 9) + pcol] = rsum;   // plain store, no RMW
    }
  }
}

// ---------- kernel 3: per-row partial reduce + loss + global mean ----------
// One wave per row (512 blocks x 4 waves): lanes read the row's 125 float4 coalesced,
// shfl_xor reduce. R9-proven (~2-3 us).
__global__ void arc_finish_kernel(const float* __restrict__ part,
                                  const float* __restrict__ lbl_logit,
                                  float* __restrict__ out) {
  const int tid  = threadIdx.x;
  const int lane = tid & 63;
  const int wave = tid >> 6;
  const int row  = blockIdx.x * 4 + wave;     // 512 blocks x 4 waves = 2048 rows
  const float4* p4 = (const float4*)(part + ((size_t)row << 9));
  float4 q0 = p4[lane];                       // entries 0..63
  float s = (q0.x + q0.y) + (q0.z + q0.w);
  if (lane < 61) {                            // entries 64..124 (125 total = 500 floats)
    float4 q1 = p4[64 + lane];
    s += (q1.x + q1.y) + (q1.z + q1.w);
  }
  #pragma unroll
  for (int off = 32; off >= 1; off >>= 1) s += __shfl_xor(s, off, 64);
  __shared__ float wsum[4];
  if (lane == 0)
    wsum[wave] = (30.0f + logf(s) - lbl_logit[row]) * (1.0f / (float)B_ROWS);
  __syncthreads();
  if (tid == 0) atomicAdd(out, wsum[0] + wsum[1] + wsum[2] + wsum[3]);
}

// ---------- launch ----------
extern "C" void kernel_launch(void* const* d_in, const int* in_sizes, int n_in,
                              void* d_out, int out_size, void* d_ws, size_t ws_size,
                              hipStream_t stream) {
  const float* x      = (const float*)d_in[0];
  const float* W      = (const float*)d_in[1];
  const int*   labels = (const int*)d_in[2];
  float* out = (float*)d_out;

  char* ws = (char*)d_ws;
  uint8_t* nx = (uint8_t*)ws;                                       // 1 MB
  uint8_t* nw = (uint8_t*)(ws + (size_t)B_ROWS * D_DIM);            // 16.4 MB
  char* p = ws + (size_t)B_ROWS * D_DIM + (size_t)V_COLS * D_DIM;
  float* lbl_logit = (float*)p;  p += (size_t)B_ROWS * 4;           // 8 KB
  float* part      = (float*)p;                                     // 2048 x 512 f32 = 4 MB

  hipLaunchKernelGGL(fused_norm_kernel, dim3((B_ROWS + V_COLS) / 4), dim3(256), 0, stream,
                     x, W, nx, nw, out);
  hipLaunchKernelGGL(arc_gemm_kernel, dim3(32 * 16 * 8), dim3(256), 0, stream,
                     nx, nw, labels, part, lbl_logit);
  hipLaunchKernelGGL(arc_finish_kernel, dim3(B_ROWS / 4), dim3(256), 0, stream,
                     part, lbl_logit, out);
}